// Round 5
// baseline (438.558 us; speedup 1.0000x reference)
//
#include <hip/hip_runtime.h>
#include <math.h>

// ---------------------------------------------------------------------------
// AttnBlock: per-edge radial-MLP attention logits + segment softmax over dst.
//
// Structure (3 stream ops):
//   memset ssum[N]=0 (double)
//   K1 edge:  dot[e] -> d_out (fp32), atomicAdd ssum[v[e]] += exp((double)dot)
//   K2 norm:  d_out[e] = (float)( exp((double)dot) / ssum[v[e]] )
//
// fp64 exp/sum/divide replaces the per-node max pass: exp range +-709 in
// double strictly dominates the achievable |dot| (LN bounds the MLP output).
//
// R8 (this round): DUAL-MLP ILP + SoA prep.
//   Evidence: VALU-busy time invariant ~78us across 4 structurally different
//   kernels => inst count is fixed; the other ~85us is stall. Attack stalls
//   with in-lane ILP (immune to occupancy caps):
//   - Block = 2 waves x 128 edges. Wave 0 runs MLP00+MLP11, wave 1 runs
//     MLP01+MLP10 (pairs the heaviest epilogue with the lightest =>
//     balanced waves). Each lane interleaves TWO independent MLP chains
//     (radial_dual): every dependency bubble fillable by the other chain.
//   - sprep stored SoA [11][128]: R7's AoS stride-12 reads were 8-way
//     bank-conflicted (3.3M conflict cycles); SoA is conflict-free both
//     sides.
//   - f0v/f1v LDS reads deferred until after the MLP trunk (VGPR relief;
//     peak live = ha/hb/h2a/h2b = 128 regs + misc).
//   - Per-wave partial dot (q.k epilogue linear in per-MLP terms) -> LDS
//     -> wave 0 reduces, writes out, fp64 atomic for its 2 edges.
// ---------------------------------------------------------------------------

#define TPB 128
#define EPB 128  // edges per block (= 2 per lane, 2 MLPs per wave)

typedef float f2 __attribute__((ext_vector_type(2)));
typedef float f4 __attribute__((ext_vector_type(4)));

static __device__ __forceinline__ f2 fma2(f2 a, f2 b, f2 c) {
    return __builtin_elementwise_fma(a, b, c);
}
static __device__ __forceinline__ f2 splat(float x) {
    f2 r;
    r.x = x;
    r.y = x;
    return r;
}
static __device__ __forceinline__ f2 mk2(float a, float b) {
    f2 r;
    r.x = a;
    r.y = b;
    return r;
}

// Dual LayerNorm(16)+ReLU, edge-pair packed, two independent states
// interleaved so the two rsqrt/horizontal chains hide each other.
static __device__ __forceinline__ void ln_relu_dual(
    f2* a, const float* __restrict__ ga, const float* __restrict__ ba,
    f2* b, const float* __restrict__ gb, const float* __restrict__ bb) {
    f2 sa = ((a[0] + a[1]) + (a[2] + a[3])) + ((a[4] + a[5]) + (a[6] + a[7])) +
            (((a[8] + a[9]) + (a[10] + a[11])) +
             ((a[12] + a[13]) + (a[14] + a[15])));
    f2 sb = ((b[0] + b[1]) + (b[2] + b[3])) + ((b[4] + b[5]) + (b[6] + b[7])) +
            (((b[8] + b[9]) + (b[10] + b[11])) +
             ((b[12] + b[13]) + (b[14] + b[15])));
    const f2 mua = sa * splat(0.0625f);
    const f2 mub = sb * splat(0.0625f);
    f2 va = splat(0.f), vb = splat(0.f);
#pragma unroll
    for (int c = 0; c < 16; ++c) {
        f2 da = a[c] - mua;
        f2 db = b[c] - mub;
        va = fma2(da, da, va);
        vb = fma2(db, db, vb);
    }
    const f2 vara = va * splat(0.0625f);
    const f2 varb = vb * splat(0.0625f);
    f2 ra, rb;
    ra.x = rsqrtf(vara.x + 1e-5f);
    ra.y = rsqrtf(vara.y + 1e-5f);
    rb.x = rsqrtf(varb.x + 1e-5f);
    rb.y = rsqrtf(varb.y + 1e-5f);
    const f2 zero = splat(0.f);
#pragma unroll
    for (int c = 0; c < 16; ++c) {
        f2 ta = (a[c] - mua) * ra;
        f2 tb = (b[c] - mub) * rb;
        a[c] = __builtin_elementwise_max(fma2(ta, splat(ga[c]), splat(ba[c])), zero);
        b[c] = __builtin_elementwise_max(fma2(tb, splat(gb[c]), splat(bb[c])), zero);
    }
}

// Two radial MLPs (layers 1..2), same inputs, different weights, interleaved.
static __device__ __forceinline__ void radial_dual(
    f2 v0, f2 v1, f2 v2, const float* __restrict__ W1A,
    const float* __restrict__ b1A, const float* __restrict__ g1A,
    const float* __restrict__ be1A, const float* __restrict__ W2A,
    const float* __restrict__ b2A, const float* __restrict__ g2A,
    const float* __restrict__ be2A, const float* __restrict__ W1B,
    const float* __restrict__ b1B, const float* __restrict__ g1B,
    const float* __restrict__ be1B, const float* __restrict__ W2B,
    const float* __restrict__ b2B, const float* __restrict__ g2B,
    const float* __restrict__ be2B, f2* h2a, f2* h2b) {
    f2 ha[16], hb[16];
#pragma unroll
    for (int c = 0; c < 16; ++c) {
        ha[c] = fma2(v0, splat(W1A[c]),
                     fma2(v1, splat(W1A[16 + c]),
                          fma2(v2, splat(W1A[32 + c]), splat(b1A[c]))));
        hb[c] = fma2(v0, splat(W1B[c]),
                     fma2(v1, splat(W1B[16 + c]),
                          fma2(v2, splat(W1B[32 + c]), splat(b1B[c]))));
    }
    ln_relu_dual(ha, g1A, be1A, hb, g1B, be1B);
#pragma unroll
    for (int c2 = 0; c2 < 16; ++c2) {
        h2a[c2] = splat(b2A[c2]);
        h2b[c2] = splat(b2B[c2]);
    }
#pragma unroll
    for (int c = 0; c < 16; ++c) {
#pragma unroll
        for (int c2 = 0; c2 < 16; ++c2) {
            h2a[c2] = fma2(ha[c], splat(W2A[c * 16 + c2]), h2a[c2]);
            h2b[c2] = fma2(hb[c], splat(W2B[c * 16 + c2]), h2b[c2]);
        }
    }
    ln_relu_dual(h2a, g2A, be2A, h2b, g2B, be2B);
}

// layer3 (OUT=4), edge-pair packed: p[oi] for oi = o*2+i
static __device__ __forceinline__ void layer3_pair4(const f2* h2,
                                                    const float* __restrict__ W3,
                                                    const float* __restrict__ b3,
                                                    f2 p[4]) {
#pragma unroll
    for (int oi = 0; oi < 4; ++oi) p[oi] = splat(b3[oi]);
#pragma unroll
    for (int c = 0; c < 16; ++c) {
#pragma unroll
        for (int oi = 0; oi < 4; ++oi)
            p[oi] = fma2(h2[c], splat(W3[c * 4 + oi]), p[oi]);
    }
}

__global__ __launch_bounds__(TPB, 3) void edge_kernel(
    const float* __restrict__ f0, const float* __restrict__ f1,
    const float* __restrict__ dist, const int* __restrict__ u,
    const int* __restrict__ v, const float* __restrict__ wq,
    const float* __restrict__ wj00, const float* __restrict__ wj01,
    const float* __restrict__ wj10, const float* __restrict__ wj11,
    const float* __restrict__ rW1, const float* __restrict__ rb1,
    const float* __restrict__ g1, const float* __restrict__ be1,
    const float* __restrict__ rW2, const float* __restrict__ rb2,
    const float* __restrict__ g2, const float* __restrict__ be2,
    const float* __restrict__ W3_00, const float* __restrict__ b3_00,
    const float* __restrict__ W3_01, const float* __restrict__ b3_01,
    const float* __restrict__ W3_10, const float* __restrict__ b3_10,
    const float* __restrict__ W3_11, const float* __restrict__ b3_11,
    float* __restrict__ out, double* __restrict__ ssum, int E) {
    __shared__ __align__(16) float s11[EPB * 27];
    __shared__ __align__(16) float s01[EPB * 3];
    __shared__ __align__(16) float s10[EPB * 3];
    __shared__ float sprep[11][EPB];  // SoA: conflict-free both sides
    __shared__ int sv[EPB];
    __shared__ f2 pdot[2][64];

    const int tid = threadIdx.x;
    const int base = blockIdx.x * EPB;
    const int rem = E - base;
    const int nE = (rem < EPB) ? rem : EPB;

    // ---- coalesced staging of per-edge wj tensors ----
    if (nE == EPB) {
        const f4* s11s = (const f4*)(wj11 + (size_t)base * 27);
        f4* s11d = (f4*)s11;
        for (int i = tid; i < EPB * 27 / 4; i += TPB) s11d[i] = s11s[i];
        if (tid < EPB * 3 / 4) {
            ((f4*)s01)[tid] = ((const f4*)(wj01 + (size_t)base * 3))[tid];
            ((f4*)s10)[tid] = ((const f4*)(wj10 + (size_t)base * 3))[tid];
        }
    } else {
        for (int i = tid; i < EPB * 27; i += TPB)
            s11[i] = (i < nE * 27) ? wj11[(size_t)base * 27 + i] : 0.f;
        for (int i = tid; i < EPB * 3; i += TPB) {
            s01[i] = (i < nE * 3) ? wj01[(size_t)base * 3 + i] : 0.f;
            s10[i] = (i < nE * 3) ? wj10[(size_t)base * 3 + i] : 0.f;
        }
    }

    // ---- shared edge prep: gathers done ONCE per slab, all 128 threads ----
    {
        const int e = base + tid;
        float p[11];
#pragma unroll
        for (int k = 0; k < 11; ++k) p[k] = 0.f;
        int vv = 0;
        if (e < E) {
            const int uu = u[e];
            vv = v[e];
            const f2 f0u = *(const f2*)(f0 + (size_t)uu * 2);
            const f2 f0v2 = *(const f2*)(f0 + (size_t)vv * 2);
            const f2 f1a = *(const f2*)(f1 + (size_t)vv * 6);
            const f2 f1b = *(const f2*)(f1 + (size_t)vv * 6 + 2);
            const f2 f1c = *(const f2*)(f1 + (size_t)vv * 6 + 4);
            p[0] = f0u.x * f0v2.x;  // vec0
            p[1] = f0u.y * f0v2.y;  // vec1
            p[2] = dist[e];         // vec2
            p[3] = f0v2.x;          // f0v0
            p[4] = f0v2.y;          // f0v1
            p[5] = f1a.x;           // f1v[0][0]
            p[6] = f1a.y;           // f1v[0][1]
            p[7] = f1b.x;           // f1v[0][2]
            p[8] = f1b.y;           // f1v[1][0]
            p[9] = f1c.x;           // f1v[1][1]
            p[10] = f1c.y;          // f1v[1][2]
        }
#pragma unroll
        for (int k = 0; k < 11; ++k) sprep[k][tid] = p[k];
        sv[tid] = vv;
    }
    __syncthreads();

    const int l = tid & 63;
    const int w = __builtin_amdgcn_readfirstlane(tid >> 6);  // wave id (uniform)

    // wave w runs MLP iA = w and MLP iB = 3-w (balances 00+11 vs 01+10)
    const int iA = w;
    const int iB = 3 - w;

    const f2 vec0 = mk2(sprep[0][l], sprep[0][l + 64]);
    const f2 vec1 = mk2(sprep[1][l], sprep[1][l + 64]);
    const f2 vec2 = mk2(sprep[2][l], sprep[2][l + 64]);

    f2 h2a[16], h2b[16];
    radial_dual(vec0, vec1, vec2,
                rW1 + iA * 48, rb1 + iA * 16, g1 + iA * 16, be1 + iA * 16,
                rW2 + iA * 256, rb2 + iA * 16, g2 + iA * 16, be2 + iA * 16,
                rW1 + iB * 48, rb1 + iB * 16, g1 + iB * 16, be1 + iB * 16,
                rW2 + iB * 256, rb2 + iB * 16, g2 + iB * 16, be2 + iB * 16,
                h2a, h2b);

    // deferred prep reads (after trunk: VGPR relief)
    const f2 f0v0 = mk2(sprep[3][l], sprep[3][l + 64]);
    const f2 f0v1 = mk2(sprep[4][l], sprep[4][l + 64]);
    f2 f1v[2][3];
    f1v[0][0] = mk2(sprep[5][l], sprep[5][l + 64]);
    f1v[0][1] = mk2(sprep[6][l], sprep[6][l + 64]);
    f1v[0][2] = mk2(sprep[7][l], sprep[7][l + 64]);
    f1v[1][0] = mk2(sprep[8][l], sprep[8][l + 64]);
    f1v[1][1] = mk2(sprep[9][l], sprep[9][l + 64]);
    f1v[1][2] = mk2(sprep[10][l], sprep[10][l + 64]);

    const int eA = base + l, eB = eA + 64;
    f2 dotp = splat(0.f);

    if (w == 0) {
        // ---- MLP00 (h2a): (l=0,k=0) ----
        {
            f2 p[4];
            layer3_pair4(h2a, W3_00, b3_00, p);
            f2 wj;
            wj.x = (eA < E) ? wj00[eA] : 0.f;
            wj.y = (eB < E) ? wj00[eB] : 0.f;
            const f2 a0 = wj * fma2(p[0], f0v0, p[1] * f0v1);
            const f2 a1 = wj * fma2(p[2], f0v0, p[3] * f0v1);
            const f2 q00 = fma2(splat(wq[0]), f0v0, splat(wq[1]) * f0v1);
            const f2 q01 = fma2(splat(wq[2]), f0v0, splat(wq[3]) * f0v1);
            dotp = fma2(q00, a0, q01 * a1);
        }
        // ---- MLP11 (h2b): (l=1,k=1) ----
        {
            f2 p[3][4];
#pragma unroll
            for (int j = 0; j < 3; ++j)
#pragma unroll
                for (int oi = 0; oi < 4; ++oi)
                    p[j][oi] = splat(b3_11[j * 4 + oi]);
#pragma unroll
            for (int c = 0; c < 16; ++c) {
#pragma unroll
                for (int j = 0; j < 3; ++j)
#pragma unroll
                    for (int oi = 0; oi < 4; ++oi)
                        p[j][oi] = fma2(h2b[c], splat(W3_11[c * 12 + j * 4 + oi]),
                                        p[j][oi]);
            }
            const float* mA = s11 + l * 27;
            const float* mB = s11 + (l + 64) * 27;
            f2 acc1[2][3];
#pragma unroll
            for (int m = 0; m < 3; ++m) {
                acc1[0][m] = splat(0.f);
                acc1[1][m] = splat(0.f);
            }
#pragma unroll
            for (int j = 0; j < 3; ++j) {
#pragma unroll
                for (int m = 0; m < 3; ++m) {
                    const f2 w0 = mk2(mA[j * 9 + m * 3 + 0], mB[j * 9 + m * 3 + 0]);
                    const f2 w1 = mk2(mA[j * 9 + m * 3 + 1], mB[j * 9 + m * 3 + 1]);
                    const f2 w2 = mk2(mA[j * 9 + m * 3 + 2], mB[j * 9 + m * 3 + 2]);
                    const f2 B0 =
                        fma2(w0, f1v[0][0], fma2(w1, f1v[0][1], w2 * f1v[0][2]));
                    const f2 B1 =
                        fma2(w0, f1v[1][0], fma2(w1, f1v[1][1], w2 * f1v[1][2]));
                    acc1[0][m] = fma2(p[j][0], B0, fma2(p[j][1], B1, acc1[0][m]));
                    acc1[1][m] = fma2(p[j][2], B0, fma2(p[j][3], B1, acc1[1][m]));
                }
            }
#pragma unroll
            for (int m = 0; m < 3; ++m) {
                const f2 q0 =
                    fma2(splat(wq[4]), f1v[0][m], splat(wq[5]) * f1v[1][m]);
                const f2 q1 =
                    fma2(splat(wq[6]), f1v[0][m], splat(wq[7]) * f1v[1][m]);
                dotp = fma2(q0, acc1[0][m], dotp);
                dotp = fma2(q1, acc1[1][m], dotp);
            }
        }
    } else {
        // ---- MLP01 (h2a): (l=0,k=1) ----
        {
            f2 p[4];
            layer3_pair4(h2a, W3_01, b3_01, p);
            const float* mA = s01 + l * 3;
            const float* mB = s01 + (l + 64) * 3;
            f2 s0 = splat(0.f), s1 = splat(0.f);
#pragma unroll
            for (int m = 0; m < 3; ++m) {
                const f2 wm = mk2(mA[m], mB[m]);
                s0 = fma2(wm, f1v[0][m], s0);
                s1 = fma2(wm, f1v[1][m], s1);
            }
            const f2 a0 = fma2(p[0], s0, p[1] * s1);
            const f2 a1 = fma2(p[2], s0, p[3] * s1);
            const f2 q00 = fma2(splat(wq[0]), f0v0, splat(wq[1]) * f0v1);
            const f2 q01 = fma2(splat(wq[2]), f0v0, splat(wq[3]) * f0v1);
            dotp = fma2(q00, a0, q01 * a1);
        }
        // ---- MLP10 (h2b): (l=1,k=0) ----
        {
            f2 p[4];
            layer3_pair4(h2b, W3_10, b3_10, p);
            const f2 t0 = fma2(p[0], f0v0, p[1] * f0v1);
            const f2 t1 = fma2(p[2], f0v0, p[3] * f0v1);
            const float* mA = s10 + l * 3;
            const float* mB = s10 + (l + 64) * 3;
#pragma unroll
            for (int m = 0; m < 3; ++m) {
                const f2 wm = mk2(mA[m], mB[m]);
                const f2 q0 =
                    fma2(splat(wq[4]), f1v[0][m], splat(wq[5]) * f1v[1][m]);
                const f2 q1 =
                    fma2(splat(wq[6]), f1v[0][m], splat(wq[7]) * f1v[1][m]);
                dotp = fma2(q0 * wm, t0, dotp);
                dotp = fma2(q1 * wm, t1, dotp);
            }
        }
    }

    pdot[w][l] = dotp;
    __syncthreads();

    if (w == 0) {
        const f2 d = pdot[0][l] + pdot[1][l];
        if (eA < E) {
            out[eA] = d.x;
            atomicAdd(&ssum[sv[l]], exp((double)d.x));
        }
        if (eB < E) {
            out[eB] = d.y;
            atomicAdd(&ssum[sv[l + 64]], exp((double)d.y));
        }
    }
}

__global__ void norm_kernel(float* __restrict__ out, const int* __restrict__ v,
                            const double* __restrict__ ssum, int E) {
    int e = blockIdx.x * blockDim.x + threadIdx.x;
    if (e >= E) return;
    const double t = exp((double)out[e]);
    out[e] = (float)(t / ssum[v[e]]);
}

extern "C" void kernel_launch(void* const* d_in, const int* in_sizes, int n_in,
                              void* d_out, int out_size, void* d_ws,
                              size_t ws_size, hipStream_t stream) {
    const float* f0 = (const float*)d_in[0];
    const float* f1 = (const float*)d_in[1];
    const float* dist = (const float*)d_in[2];
    const int* u = (const int*)d_in[3];
    const int* v = (const int*)d_in[4];
    const float* wq = (const float*)d_in[5];
    const float* wj00 = (const float*)d_in[6];
    const float* wj01 = (const float*)d_in[7];
    const float* wj10 = (const float*)d_in[8];
    const float* wj11 = (const float*)d_in[9];
    const float* rW1 = (const float*)d_in[10];
    const float* rb1 = (const float*)d_in[11];
    const float* g1 = (const float*)d_in[12];
    const float* be1 = (const float*)d_in[13];
    const float* rW2 = (const float*)d_in[14];
    const float* rb2 = (const float*)d_in[15];
    const float* g2 = (const float*)d_in[16];
    const float* be2 = (const float*)d_in[17];
    const float* W3_00 = (const float*)d_in[18];
    const float* b3_00 = (const float*)d_in[19];
    const float* W3_01 = (const float*)d_in[20];
    const float* b3_01 = (const float*)d_in[21];
    const float* W3_10 = (const float*)d_in[22];
    const float* b3_10 = (const float*)d_in[23];
    const float* W3_11 = (const float*)d_in[24];
    const float* b3_11 = (const float*)d_in[25];

    const int N = in_sizes[0] / 2;  // f0 is [N,2,1]
    const int E = in_sizes[2];      // dist is [E]

    double* ssum = (double*)d_ws;
    float* out = (float*)d_out;

    hipMemsetAsync(ssum, 0, (size_t)N * sizeof(double), stream);
    const int ge = (E + EPB - 1) / EPB;
    edge_kernel<<<ge, TPB, 0, stream>>>(
        f0, f1, dist, u, v, wq, wj00, wj01, wj10, wj11, rW1, rb1, g1, be1, rW2,
        rb2, g2, be2, W3_00, b3_00, W3_01, b3_01, W3_10, b3_10, W3_11, b3_11,
        out, ssum, E);
    const int gn = (E + 255) / 256;
    norm_kernel<<<gn, 256, 0, stream>>>(out, v, ssum, E);
}